// Round 1
// baseline (277.652 us; speedup 1.0000x reference)
//
#include <hip/hip_runtime.h>

#define B_TOTAL 8388608

__global__ __launch_bounds__(256) void trading_loss_main(
    const float* __restrict__ preds,    // [B,3]
    const int*   __restrict__ targets,  // [B]
    const float* __restrict__ pc,       // [B]
    const float* __restrict__ td,       // [B]
    float* __restrict__ sums,           // [4] in d_ws, pre-zeroed
    int nquads)                         // B/4
{
    float s_cew = 0.f, s_ce = 0.f, s_mw = 0.f, s_tr = 0.f;

    int tid = blockIdx.x * blockDim.x + threadIdx.x;
    int stride = gridDim.x * blockDim.x;

    for (int q = tid; q < nquads; q += stride) {
        // 4 samples = 12 contiguous floats of predictions (48B, 16B-aligned)
        const float4* p4 = reinterpret_cast<const float4*>(preds + (size_t)q * 12);
        float4 a = p4[0];
        float4 b = p4[1];
        float4 c = p4[2];
        float p[12] = {a.x,a.y,a.z,a.w, b.x,b.y,b.z,b.w, c.x,c.y,c.z,c.w};

        int4   t4  = reinterpret_cast<const int4*  >(targets)[q];
        float4 pc4 = reinterpret_cast<const float4*>(pc)[q];
        float4 td4 = reinterpret_cast<const float4*>(td)[q];
        int   tt[4]  = {t4.x, t4.y, t4.z, t4.w};
        float pcv[4] = {pc4.x, pc4.y, pc4.z, pc4.w};
        float tdv[4] = {td4.x, td4.y, td4.z, td4.w};

        #pragma unroll
        for (int j = 0; j < 4; ++j) {
            float p0 = p[j*3 + 0], p1 = p[j*3 + 1], p2 = p[j*3 + 2];
            float m  = fmaxf(fmaxf(p0, p1), p2);
            float e0 = __expf(p0 - m);
            float e1 = __expf(p1 - m);
            float e2 = __expf(p2 - m);
            float lse = __logf(e0 + e1 + e2);
            int   t  = tt[j];
            float pt = (t == 0) ? p0 : ((t == 1) ? p1 : p2);
            float ce = lse - (pt - m);           // -log_softmax[t]
            float aw = fabsf(pcv[j]);

            s_ce  += ce;
            s_cew += ce * aw;
            s_mw  += aw;
            bool aligned = (tdv[j] > 0.f && t == 2) || (tdv[j] < 0.f && t == 0);
            s_tr += aligned ? 1.0f : 0.0f;
        }
    }

    // wave-level butterfly reduce (wave = 64 lanes)
    #pragma unroll
    for (int off = 32; off >= 1; off >>= 1) {
        s_cew += __shfl_down(s_cew, off, 64);
        s_ce  += __shfl_down(s_ce , off, 64);
        s_mw  += __shfl_down(s_mw , off, 64);
        s_tr  += __shfl_down(s_tr , off, 64);
    }

    __shared__ float red[4][4];   // 4 waves per 256-thread block
    int lane = threadIdx.x & 63;
    int wave = threadIdx.x >> 6;
    if (lane == 0) {
        red[wave][0] = s_cew;
        red[wave][1] = s_ce;
        red[wave][2] = s_mw;
        red[wave][3] = s_tr;
    }
    __syncthreads();

    if (threadIdx.x == 0) {
        float r0 = 0.f, r1 = 0.f, r2 = 0.f, r3 = 0.f;
        #pragma unroll
        for (int w = 0; w < 4; ++w) {
            r0 += red[w][0]; r1 += red[w][1]; r2 += red[w][2]; r3 += red[w][3];
        }
        atomicAdd(&sums[0], r0);
        atomicAdd(&sums[1], r1);
        atomicAdd(&sums[2], r2);
        atomicAdd(&sums[3], r3);
    }
}

__global__ void trading_loss_final(const float* __restrict__ sums,
                                   float* __restrict__ out)
{
    const float invB = 1.0f / (float)B_TOTAL;
    float cew_mean = sums[0] * invB;              // mean(ce * |pc|)
    float ce_mean  = sums[1] * invB;              // mean(ce)
    float mw_mean  = sums[2] * invB + 1e-8f;      // mean(|pc|) + EPS
    float tr_mean  = -0.1f * sums[3] * invB;      // mean(trend_alignment)
    out[0] = 0.85f * (cew_mean / mw_mean) + 0.15f * ce_mean + 0.1f * tr_mean;
}

extern "C" void kernel_launch(void* const* d_in, const int* in_sizes, int n_in,
                              void* d_out, int out_size, void* d_ws, size_t ws_size,
                              hipStream_t stream) {
    const float* preds   = (const float*)d_in[0];
    const int*   targets = (const int*  )d_in[1];
    const float* pc      = (const float*)d_in[2];
    const float* td      = (const float*)d_in[3];
    float* out  = (float*)d_out;
    float* sums = (float*)d_ws;

    // d_ws is poisoned 0xAA before every launch — zero the accumulators.
    hipMemsetAsync(sums, 0, 4 * sizeof(float), stream);

    int nquads = in_sizes[1] / 4;   // B / 4

    trading_loss_main<<<2048, 256, 0, stream>>>(preds, targets, pc, td, sums, nquads);
    trading_loss_final<<<1, 1, 0, stream>>>(sums, out);
}